// Round 1
// baseline (432.905 us; speedup 1.0000x reference)
//
#include <hip/hip_runtime.h>

// Model_47510928228872: 2-layer bidirectional LSTM (H=3) + linear + sigmoid.
// B=8192, T=512, D_in=3. fp32 throughout.
//
// Plan:
//  K1: layer-0 BACKWARD. 4 lanes per batch elem (lane j<3 owns hidden j,
//      computes gates i[j],f[j],g[j],o[j] locally; h broadcast via shfl).
//      Stores y0_bwd to ws as [T][B][3] (coalesced, consumed by K2 in t order).
//  K2: layer-0 FORWARD + layer-1 FORWARD fused, 8 lanes per batch elem.
//      Lanes 0-3 = l0 cell, lanes 4-7 = l1 cell, staggered by one step
//      (l1 processes t-1 while l0 processes t). Single uniform code path.
//      Epilogue: layer-1 backward needs only ONE step (reverse scan's output
//      at t=T-1 is one step from zero init), then W_lin dot + sigmoid.

#define B_ 8192
#define T_ 512

__device__ __forceinline__ float rcp_(float x)  { return __builtin_amdgcn_rcpf(x); }
__device__ __forceinline__ float exp2_(float x) { return __builtin_amdgcn_exp2f(x); }

// NaN-safe fast sigmoid/tanh (saturate correctly at +/-inf of exp2):
__device__ __forceinline__ float sigm_(float x) {
  return rcp_(1.0f + exp2_(-1.4426950408889634f * x));
}
__device__ __forceinline__ float tanh_(float x) {
  return 1.0f - 2.0f * rcp_(1.0f + exp2_(2.8853900817779268f * x));
}

// ---------------- Kernel 1: layer-0 backward ----------------
__global__ __launch_bounds__(256) void lstm_l0_bwd(
    const float* __restrict__ x,      // [B][T][3]
    const float* __restrict__ Wih,    // [12][3]
    const float* __restrict__ Whh,    // [12][3]
    const float* __restrict__ bih,
    const float* __restrict__ bhh,
    float* __restrict__ y0b)          // [T][B][3]
{
  int tid = blockIdx.x * 256 + threadIdx.x;
  int b   = tid >> 2;           // batch element
  int jl  = tid & 3;            // lane within group (3 active)
  if (b >= B_) return;
  int j = (jl < 3) ? jl : 0;    // lane 3 duplicates j=0, never stores/sourced

  // Per-lane weights: rows {j, 3+j, 6+j, 9+j} = i[j], f[j], g[j], o[j]
  float wih[4][3], whh[4][3], bias[4];
#pragma unroll
  for (int g = 0; g < 4; ++g) {
    int r = g * 3 + j;
#pragma unroll
    for (int k = 0; k < 3; ++k) { wih[g][k] = Wih[r*3+k]; whh[g][k] = Whh[r*3+k]; }
    bias[g] = bih[r] + bhh[r];
  }

  float h = 0.f, c = 0.f;
  float hb0 = 0.f, hb1 = 0.f, hb2 = 0.f;   // broadcast h (all lanes)
  const float* xb = x + (size_t)b * (T_ * 3);

  for (int t = T_ - 1; t >= 0; --t) {
    float x0 = xb[t*3+0], x1 = xb[t*3+1], x2 = xb[t*3+2];
    float p[4];
#pragma unroll
    for (int g = 0; g < 4; ++g)
      p[g] = bias[g] + wih[g][0]*x0 + wih[g][1]*x1 + wih[g][2]*x2
                     + whh[g][0]*hb0 + whh[g][1]*hb1 + whh[g][2]*hb2;
    float ig = sigm_(p[0]), fg = sigm_(p[1]), gg = tanh_(p[2]), og = sigm_(p[3]);
    c = fg * c + ig * gg;
    h = og * tanh_(c);
    hb0 = __shfl(h, 0, 4); hb1 = __shfl(h, 1, 4); hb2 = __shfl(h, 2, 4);
    if (jl < 3) y0b[((size_t)t * B_ + b) * 3 + jl] = h;
  }
}

// ---------------- Kernel 2: l0-fwd + l1-fwd fused, + epilogue ----------------
__global__ __launch_bounds__(256) void lstm_fused_fwd(
    const float* __restrict__ x,
    const float* __restrict__ Wih0, const float* __restrict__ Whh0,
    const float* __restrict__ bih0, const float* __restrict__ bhh0,
    const float* __restrict__ Wih1, const float* __restrict__ Whh1,
    const float* __restrict__ bih1, const float* __restrict__ bhh1,
    const float* __restrict__ Wih1r, const float* __restrict__ Whh1r,
    const float* __restrict__ bih1r, const float* __restrict__ bhh1r,
    const float* __restrict__ Wlin, const float* __restrict__ blin,
    const float* __restrict__ y0b,   // [T][B][3]
    float* __restrict__ out)         // [B]
{
  int tid  = blockIdx.x * 256 + threadIdx.x;
  int b    = tid >> 3;
  int lane = tid & 7;
  if (b >= B_) return;
  bool role1 = lane >= 4;               // layer-1 cell lanes
  int j  = role1 ? (lane - 4) : lane;   // hidden index (3 active per role)
  int jc = (j < 3) ? j : 2;             // clamp idle lanes 3,7

  // Unified 6-input cell. l0 lanes: inputs = (x0,x1,x2,0,0,0), cols 3-5 zero.
  float wih[4][6], whh[4][3], bias[4];
  if (!role1) {
#pragma unroll
    for (int g = 0; g < 4; ++g) {
      int r = g * 3 + jc;
#pragma unroll
      for (int k = 0; k < 3; ++k) {
        wih[g][k] = Wih0[r*3+k]; wih[g][3+k] = 0.f; whh[g][k] = Whh0[r*3+k];
      }
      bias[g] = bih0[r] + bhh0[r];
    }
  } else {
#pragma unroll
    for (int g = 0; g < 4; ++g) {
      int r = g * 3 + jc;
#pragma unroll
      for (int k = 0; k < 6; ++k) wih[g][k] = Wih1[r*6+k];
#pragma unroll
      for (int k = 0; k < 3; ++k) whh[g][k] = Whh1[r*3+k];
      bias[g] = bih1[r] + bhh1[r];
    }
  }

  float h = 0.f, c = 0.f;
  float ha0 = 0.f, ha1 = 0.f, ha2 = 0.f;  // role-own previous h (Whh term)
  float hb0 = 0.f, hb1 = 0.f, hb2 = 0.f;  // layer-0 h broadcast (l1 input)
  const float* xb = x + (size_t)b * (T_ * 3);

  // Staggered pipeline: iteration tt: l0 processes t=tt, l1 processes t=tt-1.
  for (int tt = 0; tt <= T_; ++tt) {
    int tl0 = (tt < T_) ? tt : (T_ - 1);
    int tl1 = (tt >= 1) ? (tt - 1) : 0;
    const float* ldp = role1 ? (y0b + ((size_t)tl1 * B_ + b) * 3)
                             : (xb + tl0 * 3);
    float L0 = ldp[0], L1 = ldp[1], L2 = ldp[2];
    float v0 = role1 ? hb0 : L0;
    float v1 = role1 ? hb1 : L1;
    float v2 = role1 ? hb2 : L2;
    float v3 = role1 ? L0 : 0.f;
    float v4 = role1 ? L1 : 0.f;
    float v5 = role1 ? L2 : 0.f;

    float p[4];
#pragma unroll
    for (int g = 0; g < 4; ++g)
      p[g] = bias[g] + wih[g][0]*v0 + wih[g][1]*v1 + wih[g][2]*v2
                     + wih[g][3]*v3 + wih[g][4]*v4 + wih[g][5]*v5
                     + whh[g][0]*ha0 + whh[g][1]*ha1 + whh[g][2]*ha2;
    float ig = sigm_(p[0]), fg = sigm_(p[1]), gg = tanh_(p[2]), og = sigm_(p[3]);
    float cn = fg * c + ig * gg;
    float hn = og * tanh_(cn);
    bool valid = role1 ? (tt >= 1) : (tt < T_);
    c = valid ? cn : c;
    h = valid ? hn : h;

    int base = lane & 4;  // role-own broadcast base (0 or 4)
    ha0 = __shfl(h, base + 0, 8);
    ha1 = __shfl(h, base + 1, 8);
    ha2 = __shfl(h, base + 2, 8);
    hb0 = __shfl(h, 0, 8);
    hb1 = __shfl(h, 1, 8);
    hb2 = __shfl(h, 2, 8);
  }
  // Post-loop: lanes 0-2 hold h0(T-1); lanes 4-6 hold h1_fwd(T-1);
  // hb0..2 = h0(T-1) on all lanes.

  // Layer-1 BACKWARD, single step at t=T-1 from zero state (all lanes compute).
  float h1b;
  {
    float wr[4][6], br[4];
#pragma unroll
    for (int g = 0; g < 4; ++g) {
      int r = g * 3 + jc;
#pragma unroll
      for (int k = 0; k < 6; ++k) wr[g][k] = Wih1r[r*6+k];
      br[g] = bih1r[r] + bhh1r[r];
    }
    const float* yb = y0b + ((size_t)(T_ - 1) * B_ + b) * 3;
    float u3 = yb[0], u4 = yb[1], u5 = yb[2];
    float q[4];
#pragma unroll
    for (int g = 0; g < 4; ++g)
      q[g] = br[g] + wr[g][0]*hb0 + wr[g][1]*hb1 + wr[g][2]*hb2
                   + wr[g][3]*u3  + wr[g][4]*u4  + wr[g][5]*u5;
    float ig = sigm_(q[0]), gg = tanh_(q[2]), og = sigm_(q[3]);
    float cb = ig * gg;                 // c_prev = 0, so f-gate drops out
    h1b = og * tanh_(cb);
  }

  // Final: out[b] = sigmoid(Wlin . [h1_fwd(0:3), h1_bwd(0:3)] + blin)
  float part = 0.f;
  if (role1) { if (j < 3) part = Wlin[j]     * h;   }
  else       { if (j < 3) part = Wlin[3 + j] * h1b; }
  part += __shfl_xor(part, 1, 8);
  part += __shfl_xor(part, 2, 8);
  part += __shfl_xor(part, 4, 8);
  if (lane == 0) out[b] = sigm_(part + blin[0]);
}

extern "C" void kernel_launch(void* const* d_in, const int* in_sizes, int n_in,
                              void* d_out, int out_size, void* d_ws, size_t ws_size,
                              hipStream_t stream) {
  const float* x        = (const float*)d_in[0];
  const float* W_ih_l0  = (const float*)d_in[1];
  const float* W_hh_l0  = (const float*)d_in[2];
  const float* b_ih_l0  = (const float*)d_in[3];
  const float* b_hh_l0  = (const float*)d_in[4];
  const float* W_ih_l0r = (const float*)d_in[5];
  const float* W_hh_l0r = (const float*)d_in[6];
  const float* b_ih_l0r = (const float*)d_in[7];
  const float* b_hh_l0r = (const float*)d_in[8];
  const float* W_ih_l1  = (const float*)d_in[9];
  const float* W_hh_l1  = (const float*)d_in[10];
  const float* b_ih_l1  = (const float*)d_in[11];
  const float* b_hh_l1  = (const float*)d_in[12];
  const float* W_ih_l1r = (const float*)d_in[13];
  const float* W_hh_l1r = (const float*)d_in[14];
  const float* b_ih_l1r = (const float*)d_in[15];
  const float* b_hh_l1r = (const float*)d_in[16];
  const float* W_lin    = (const float*)d_in[17];
  const float* b_lin    = (const float*)d_in[18];

  float* y0b = (float*)d_ws;   // [T][B][3] fp32 = 48 MB
  float* out = (float*)d_out;

  // K1: 8192 groups * 4 lanes = 32768 threads
  lstm_l0_bwd<<<(B_ * 4) / 256, 256, 0, stream>>>(
      x, W_ih_l0r, W_hh_l0r, b_ih_l0r, b_hh_l0r, y0b);

  // K2: 8192 groups * 8 lanes = 65536 threads
  lstm_fused_fwd<<<(B_ * 8) / 256, 256, 0, stream>>>(
      x, W_ih_l0, W_hh_l0, b_ih_l0, b_hh_l0,
      W_ih_l1, W_hh_l1, b_ih_l1, b_hh_l1,
      W_ih_l1r, W_hh_l1r, b_ih_l1r, b_hh_l1r,
      W_lin, b_lin, y0b, out);
}

// Round 2
// 214.889 us; speedup vs baseline: 2.0146x; 2.0146x over previous
//
#include <hip/hip_runtime.h>

// Model_47510928228872: 2-layer bidirectional LSTM (H=3) + linear + sigmoid.
// B=8192, T=512, fp32. Latency-bound -> register-double-buffered prefetch of
// 8-timestep blocks + DPP (quad_perm / row_shr:4) instead of ds_bpermute shfl.
//
// K1: layer-0 backward, 4 lanes/batch (lane j owns hidden j, gates i,f,g,o[j]).
//     Writes y0_bwd as [B][T][3].
// K2: layer-0 fwd (quad 0) + layer-1 fwd (quad 1) staggered by 1 step, then
//     1-step layer-1 bwd (reverse scan output at T-1 is one step from zero
//     state) + linear + sigmoid.

#define B_ 8192
#define T_ 512

__device__ __forceinline__ float rcp_(float x)  { return __builtin_amdgcn_rcpf(x); }
__device__ __forceinline__ float exp2_(float x) { return __builtin_amdgcn_exp2f(x); }
__device__ __forceinline__ float sigm_(float x) {
  return rcp_(1.0f + exp2_(-1.4426950408889634f * x));
}
__device__ __forceinline__ float tanh_(float x) {
  return 1.0f - 2.0f * rcp_(1.0f + exp2_(2.8853900817779268f * x));
}

// DPP cross-lane (VALU, ~2cy — replaces ds_bpermute ~40cy on the h-chain)
template <int CTRL>
__device__ __forceinline__ float dppf(float v) {
  int s = __float_as_int(v);
  return __int_as_float(__builtin_amdgcn_update_dpp(s, s, CTRL, 0xF, 0xF, false));
}
#define QB0 0x00   // quad_perm [0,0,0,0] : broadcast lane0 of each quad
#define QB1 0x55   // quad_perm [1,1,1,1]
#define QB2 0xAA   // quad_perm [2,2,2,2]
#define SHR4 0x114 // row_shr:4 : lane i <- lane i-4 (quad1 <- quad0)

// ---------------- Kernel 1: layer-0 backward ----------------
__global__ __launch_bounds__(256, 1) void lstm_l0_bwd(
    const float* __restrict__ x,      // [B][T][3]
    const float* __restrict__ Wih, const float* __restrict__ Whh,
    const float* __restrict__ bih, const float* __restrict__ bhh,
    float* __restrict__ y0b)          // [B][T][3]
{
  int tid = blockIdx.x * 256 + threadIdx.x;
  int b = tid >> 2, jl = tid & 3;
  int j = (jl < 3) ? jl : 0;          // lane 3 duplicates j=0 (never stored)

  float wih[4][3], whh[4][3], bias[4];
#pragma unroll
  for (int g = 0; g < 4; ++g) {
    int r = g * 3 + j;
#pragma unroll
    for (int k = 0; k < 3; ++k) { wih[g][k] = Wih[r*3+k]; whh[g][k] = Whh[r*3+k]; }
    bias[g] = bih[r] + bhh[r];
  }

  float h = 0.f, c = 0.f, hb0 = 0.f, hb1 = 0.f, hb2 = 0.f;
  const float* xb = x   + (size_t)b * (T_ * 3);
  float*       yw = y0b + (size_t)b * (T_ * 3) + jl;

  float A[24], Bf[24];
  auto LD = [&](int blk, float* dst) {           // 8 t's = 24 floats = 96B, 16-aligned
    const float4* q = (const float4*)(xb + blk * 24);
#pragma unroll
    for (int k = 0; k < 6; ++k) {
      float4 v = q[k];
      dst[k*4+0] = v.x; dst[k*4+1] = v.y; dst[k*4+2] = v.z; dst[k*4+3] = v.w;
    }
  };
  auto STEP = [&](float x0, float x1, float x2, int t) {
    float p[4];
#pragma unroll
    for (int g = 0; g < 4; ++g)
      p[g] = bias[g] + wih[g][0]*x0 + wih[g][1]*x1 + wih[g][2]*x2
                     + whh[g][0]*hb0 + whh[g][1]*hb1 + whh[g][2]*hb2;
    float ig = sigm_(p[0]), fg = sigm_(p[1]), gg = tanh_(p[2]), og = sigm_(p[3]);
    c = fg * c + ig * gg;
    h = og * tanh_(c);
    hb0 = dppf<QB0>(h); hb1 = dppf<QB1>(h); hb2 = dppf<QB2>(h);
    if (jl < 3) yw[t * 3] = h;
  };
  auto PROC = [&](int blk, const float* v) {     // t descending within block
#pragma unroll
    for (int s = 7; s >= 0; --s) STEP(v[s*3], v[s*3+1], v[s*3+2], blk*8 + s);
  };

  LD(63, A); LD(62, Bf);
  for (int blk = 63; blk >= 1; blk -= 2) {
    PROC(blk, A);
    if (blk >= 3) LD(blk - 2, A);
    PROC(blk - 1, Bf);
    if (blk >= 3) LD(blk - 3, Bf);
  }
}

// ---------------- Kernel 2: l0-fwd + l1-fwd fused + epilogue ----------------
__global__ __launch_bounds__(256, 1) void lstm_fused_fwd(
    const float* __restrict__ x,
    const float* __restrict__ Wih0, const float* __restrict__ Whh0,
    const float* __restrict__ bih0, const float* __restrict__ bhh0,
    const float* __restrict__ Wih1, const float* __restrict__ Whh1,
    const float* __restrict__ bih1, const float* __restrict__ bhh1,
    const float* __restrict__ Wih1r, const float* __restrict__ Whh1r,
    const float* __restrict__ bih1r, const float* __restrict__ bhh1r,
    const float* __restrict__ Wlin, const float* __restrict__ blin,
    const float* __restrict__ y0b,   // [B][T][3]
    float* __restrict__ out)         // [B]
{
  int tid = blockIdx.x * 256 + threadIdx.x;
  int b = tid >> 3, lane = tid & 7;
  bool role1 = lane >= 4;               // quad 1 = layer-1 cell
  int j  = role1 ? (lane - 4) : lane;
  int jc = (j < 3) ? j : 2;

  float wih[4][6], whh[4][3], bias[4];
  if (!role1) {
#pragma unroll
    for (int g = 0; g < 4; ++g) {
      int r = g * 3 + jc;
#pragma unroll
      for (int k = 0; k < 3; ++k) {
        wih[g][k] = Wih0[r*3+k]; wih[g][3+k] = 0.f; whh[g][k] = Whh0[r*3+k];
      }
      bias[g] = bih0[r] + bhh0[r];
    }
  } else {
#pragma unroll
    for (int g = 0; g < 4; ++g) {
      int r = g * 3 + jc;
#pragma unroll
      for (int k = 0; k < 6; ++k) wih[g][k] = Wih1[r*6+k];
#pragma unroll
      for (int k = 0; k < 3; ++k) whh[g][k] = Whh1[r*3+k];
      bias[g] = bih1[r] + bhh1[r];
    }
  }

  float h = 0.f, c = 0.f;
  float ha0 = 0.f, ha1 = 0.f, ha2 = 0.f;  // role-own h(t-1), via quad_perm
  float hb0 = 0.f, hb1 = 0.f, hb2 = 0.f;  // layer-0 h, via row_shr:4
  int sh = role1 ? 1 : 0;                 // layer-1 lags one step
  const float* baseR = (role1 ? y0b : x) + (size_t)b * (T_ * 3);

  // Preload y0b[b][T-1]: input of l1-fwd's final step AND of the 1-step l1-bwd.
  const float* up = y0b + (size_t)b * (T_ * 3) + (T_ - 1) * 3;
  float ub0 = up[0], ub1 = up[1], ub2 = up[2];

  float A[24], Bf[24];
  auto LD = [&](int blk, float* dst) {
    const float* p = baseR + ((size_t)(blk * 8 - sh)) * 3;
#pragma unroll
    for (int k = 0; k < 24; ++k) dst[k] = p[k];
  };
  auto LDc = [&](float* dst) {            // block 0: clamp t=-1 (value unused)
#pragma unroll
    for (int s = 0; s < 8; ++s) {
      int t = s - sh; t = (t < 0) ? 0 : t;
      const float* p = baseR + t * 3;
      dst[s*3] = p[0]; dst[s*3+1] = p[1]; dst[s*3+2] = p[2];
    }
  };
  auto STEP = [&](float L0, float L1, float L2, bool valid) {
    float v0 = role1 ? hb0 : L0;
    float v1 = role1 ? hb1 : L1;
    float v2 = role1 ? hb2 : L2;
    // cols 3..5: role0 weights are zero, so feeding L harmlessly is correct
    float p[4];
#pragma unroll
    for (int g = 0; g < 4; ++g)
      p[g] = bias[g] + wih[g][0]*v0 + wih[g][1]*v1 + wih[g][2]*v2
                     + wih[g][3]*L0 + wih[g][4]*L1 + wih[g][5]*L2
                     + whh[g][0]*ha0 + whh[g][1]*ha1 + whh[g][2]*ha2;
    float ig = sigm_(p[0]), fg = sigm_(p[1]), gg = tanh_(p[2]), og = sigm_(p[3]);
    float cn = fg * c + ig * gg;
    float hn = og * tanh_(cn);
    c = valid ? cn : c;
    h = valid ? hn : h;
    ha0 = dppf<QB0>(h); ha1 = dppf<QB1>(h); ha2 = dppf<QB2>(h);
    hb0 = dppf<SHR4>(ha0); hb1 = dppf<SHR4>(ha1); hb2 = dppf<SHR4>(ha2);
  };
  auto PROC = [&](int blk, const float* v) {
#pragma unroll
    for (int s = 0; s < 8; ++s) {
      int tt = blk * 8 + s;
      bool valid = role1 ? (tt > 0) : true;
      STEP(v[s*3], v[s*3+1], v[s*3+2], valid);
    }
  };

  LDc(A); LD(1, Bf);
  for (int blk = 0; blk < 64; blk += 2) {
    PROC(blk, A);
    if (blk + 2 < 64) LD(blk + 2, A);
    PROC(blk + 1, Bf);
    if (blk + 3 < 64) LD(blk + 3, Bf);
  }
  // Final step tt=512: l1 consumes y0b[T-1] (preloaded); l0 lanes invalid.
  STEP(ub0, ub1, ub2, role1);
  // Now: role1 lanes 4-6 hold h1_fwd[j](T-1); ha on role0 lanes / hb on role1
  // lanes both hold h0_fwd(T-1)[k].

  // Layer-1 backward: exactly one step from zero state (all lanes compute).
  float e0 = role1 ? hb0 : ha0;
  float e1 = role1 ? hb1 : ha1;
  float e2 = role1 ? hb2 : ha2;
  float h1b;
  {
    float wr[4][6], br[4];
#pragma unroll
    for (int g = 0; g < 4; ++g) {
      int r = g * 3 + jc;
#pragma unroll
      for (int k = 0; k < 6; ++k) wr[g][k] = Wih1r[r*6+k];
      br[g] = bih1r[r] + bhh1r[r];
    }
    float q[4];
#pragma unroll
    for (int g = 0; g < 4; ++g)
      q[g] = br[g] + wr[g][0]*e0 + wr[g][1]*e1 + wr[g][2]*e2
                   + wr[g][3]*ub0 + wr[g][4]*ub1 + wr[g][5]*ub2;
    float ig = sigm_(q[0]), gg = tanh_(q[2]), og = sigm_(q[3]);
    h1b = og * tanh_(ig * gg);          // c_prev = 0 -> f-gate drops out
  }

  float part = 0.f;
  if (role1) { if (j < 3) part = Wlin[j]     * h;   }
  else       { if (j < 3) part = Wlin[3 + j] * h1b; }
  part += __shfl_xor(part, 1, 8);
  part += __shfl_xor(part, 2, 8);
  part += __shfl_xor(part, 4, 8);
  if (lane == 0) out[b] = sigm_(part + blin[0]);
}

extern "C" void kernel_launch(void* const* d_in, const int* in_sizes, int n_in,
                              void* d_out, int out_size, void* d_ws, size_t ws_size,
                              hipStream_t stream) {
  const float* x        = (const float*)d_in[0];
  const float* W_ih_l0  = (const float*)d_in[1];
  const float* W_hh_l0  = (const float*)d_in[2];
  const float* b_ih_l0  = (const float*)d_in[3];
  const float* b_hh_l0  = (const float*)d_in[4];
  const float* W_ih_l0r = (const float*)d_in[5];
  const float* W_hh_l0r = (const float*)d_in[6];
  const float* b_ih_l0r = (const float*)d_in[7];
  const float* b_hh_l0r = (const float*)d_in[8];
  const float* W_ih_l1  = (const float*)d_in[9];
  const float* W_hh_l1  = (const float*)d_in[10];
  const float* b_ih_l1  = (const float*)d_in[11];
  const float* b_hh_l1  = (const float*)d_in[12];
  const float* W_ih_l1r = (const float*)d_in[13];
  const float* W_hh_l1r = (const float*)d_in[14];
  const float* b_ih_l1r = (const float*)d_in[15];
  const float* b_hh_l1r = (const float*)d_in[16];
  const float* W_lin    = (const float*)d_in[17];
  const float* b_lin    = (const float*)d_in[18];

  float* y0b = (float*)d_ws;   // [B][T][3] fp32 = 48 MB
  float* out = (float*)d_out;

  lstm_l0_bwd<<<(B_ * 4) / 256, 256, 0, stream>>>(
      x, W_ih_l0r, W_hh_l0r, b_ih_l0r, b_hh_l0r, y0b);

  lstm_fused_fwd<<<(B_ * 8) / 256, 256, 0, stream>>>(
      x, W_ih_l0, W_hh_l0, b_ih_l0, b_hh_l0,
      W_ih_l1, W_hh_l1, b_ih_l1, b_hh_l1,
      W_ih_l1r, W_hh_l1r, b_ih_l1r, b_hh_l1r,
      W_lin, b_lin, y0b, out);
}

// Round 3
// 171.405 us; speedup vs baseline: 2.5256x; 1.2537x over previous
//
#include <hip/hip_runtime.h>

// Model_47510928228872: 2-layer bidirectional LSTM (H=3) + linear + sigmoid.
// B=8192, T=512, fp32. Issue-bound -> packed fp32 (v_pk_fma_f32) gate math,
// float4 block prefetch pinned with sched_barrier, DPP cross-lane h exchange.
//
// y0b layout: [B][T][3] SHIFTED: slot t holds h_bwd(t-1); h_bwd(T-1) -> slot 0.
// This makes K2's layer-1 (lagging one step) read slot tt directly = aligned
// 96B blocks identical to layer-0's x addressing.

#define B_ 8192
#define T_ 512
#define LOG2E 1.4426950408889634f

typedef float v2f __attribute__((ext_vector_type(2)));

__device__ __forceinline__ float rcp_(float x)  { return __builtin_amdgcn_rcpf(x); }
__device__ __forceinline__ float exp2_(float x) { return __builtin_amdgcn_exp2f(x); }
__device__ __forceinline__ float sigm_(float x) {
  return rcp_(1.0f + exp2_(-LOG2E * x));
}
__device__ __forceinline__ float tanh_(float x) {
  return 1.0f - 2.0f * rcp_(1.0f + exp2_(2.0f * LOG2E * x));
}
__device__ __forceinline__ v2f sp(float s) { return (v2f){s, s}; }
__device__ __forceinline__ v2f pkfma(v2f a, float b, v2f c) {
  return __builtin_elementwise_fma(a, sp(b), c);
}

template <int CTRL>
__device__ __forceinline__ float dppf(float v) {
  int s = __float_as_int(v);
  return __int_as_float(__builtin_amdgcn_update_dpp(s, s, CTRL, 0xF, 0xF, false));
}
#define QB0 0x00   // quad_perm broadcast lane0 of quad
#define QB1 0x55
#define QB2 0xAA
#define SHR4 0x114 // row_shr:4 (quad1 <- quad0)

// float4-array element access with compile-time index
__device__ __forceinline__ float el(const float4* a, int i) {
  const float4 v = a[i >> 2];
  const int r = i & 3;
  return r == 0 ? v.x : r == 1 ? v.y : r == 2 ? v.z : v.w;
}

// ---------------- Kernel 1: layer-0 backward ----------------
__global__ __launch_bounds__(256, 1) void lstm_l0_bwd(
    const float* __restrict__ x,      // [B][T][3]
    const float* __restrict__ Wih, const float* __restrict__ Whh,
    const float* __restrict__ bih, const float* __restrict__ bhh,
    float* __restrict__ y0b)          // [B][T][3], shifted by +1 slot
{
  int tid = blockIdx.x * 256 + threadIdx.x;
  int b = tid >> 2, jl = tid & 3;
  int j = (jl < 3) ? jl : 0;          // lane 3 duplicates j=0 (never stored)

  // Packed weights: [k] = (row_i, row_f) / (row_g, row_o) for hidden j.
  v2f wif[6], wgo[6];
#pragma unroll
  for (int k = 0; k < 3; ++k) {
    wif[k]   = (v2f){ Wih[j*3+k],     Wih[(3+j)*3+k] };
    wif[3+k] = (v2f){ Whh[j*3+k],     Whh[(3+j)*3+k] };
    wgo[k]   = (v2f){ Wih[(6+j)*3+k], Wih[(9+j)*3+k] };
    wgo[3+k] = (v2f){ Whh[(6+j)*3+k], Whh[(9+j)*3+k] };
  }
  v2f bif = (v2f){ bih[j]+bhh[j],     bih[3+j]+bhh[3+j] };
  v2f bgo = (v2f){ bih[6+j]+bhh[6+j], bih[9+j]+bhh[9+j] };

  float h = 0.f, c = 0.f, hb0 = 0.f, hb1 = 0.f, hb2 = 0.f;
  const float4* xq = (const float4*)(x + (size_t)b * (T_ * 3));
  float* yw = y0b + (size_t)b * (T_ * 3) + jl;

  float4 A4[6], B4[6];
  auto LD = [&](int blk, float4* dst) {
#pragma unroll
    for (int k = 0; k < 6; ++k) dst[k] = xq[blk * 6 + k];
    __builtin_amdgcn_sched_barrier(0);   // pin prefetch issue point
  };
  auto STEP = [&](float x0, float x1, float x2, int t) {
    // two-chain accumulation to shorten dependency depth
    v2f aif = pkfma(wif[0], x0, bif);
    aif = pkfma(wif[1], x1, aif);
    aif = pkfma(wif[2], x2, aif);
    v2f uif = wif[3] * sp(hb0);
    uif = pkfma(wif[4], hb1, uif);
    uif = pkfma(wif[5], hb2, uif);
    v2f pif = aif + uif;
    v2f ago = pkfma(wgo[0], x0, bgo);
    ago = pkfma(wgo[1], x1, ago);
    ago = pkfma(wgo[2], x2, ago);
    v2f ugo = wgo[3] * sp(hb0);
    ugo = pkfma(wgo[4], hb1, ugo);
    ugo = pkfma(wgo[5], hb2, ugo);
    v2f pgo = ago + ugo;

    v2f eif = pif * sp(-LOG2E);
    float ig = rcp_(1.f + exp2_(eif.x));
    float fg = rcp_(1.f + exp2_(eif.y));
    float gg = tanh_(pgo.x);
    float og = sigm_(pgo.y);
    c = fg * c + ig * gg;
    h = og * tanh_(c);
    hb0 = dppf<QB0>(h); hb1 = dppf<QB1>(h); hb2 = dppf<QB2>(h);
    if (jl < 3) yw[(((t + 1) & (T_ - 1))) * 3] = h;   // shifted store
  };
  auto PROC = [&](int blk, const float4* v) {
#pragma unroll
    for (int s = 7; s >= 0; --s) STEP(el(v,s*3), el(v,s*3+1), el(v,s*3+2), blk*8+s);
  };

  LD(63, A4); LD(62, B4);
  for (int blk = 63; blk >= 1; blk -= 2) {
    PROC(blk, A4);
    if (blk >= 3) LD(blk - 2, A4);
    PROC(blk - 1, B4);
    if (blk >= 3) LD(blk - 3, B4);
  }
}

// ---------------- Kernel 2: l0-fwd + l1-fwd fused + epilogue ----------------
__global__ __launch_bounds__(256, 1) void lstm_fused_fwd(
    const float* __restrict__ x,
    const float* __restrict__ Wih0, const float* __restrict__ Whh0,
    const float* __restrict__ bih0, const float* __restrict__ bhh0,
    const float* __restrict__ Wih1, const float* __restrict__ Whh1,
    const float* __restrict__ bih1, const float* __restrict__ bhh1,
    const float* __restrict__ Wih1r, const float* __restrict__ Whh1r,
    const float* __restrict__ bih1r, const float* __restrict__ bhh1r,
    const float* __restrict__ Wlin, const float* __restrict__ blin,
    const float* __restrict__ y0b,   // [B][T][3] shifted
    float* __restrict__ out)         // [B]
{
  int tid = blockIdx.x * 256 + threadIdx.x;
  int b = tid >> 3, lane = tid & 7;
  bool role1 = lane >= 4;               // quad 1 = layer-1 cell
  int j  = role1 ? (lane - 4) : lane;
  int jc = (j < 3) ? j : 2;

  // Unified 9-input packed cell: inputs m0..m8 =
  //   role0: (x0,x1,x2, x0,x1,x2[*0], ha0,ha1,ha2)
  //   role1: (hb0,hb1,hb2, L0,L1,L2,  ha0,ha1,ha2)
  v2f wif[9], wgo[9];
  v2f bif, bgo;
  if (!role1) {
#pragma unroll
    for (int k = 0; k < 3; ++k) {
      wif[k]   = (v2f){ Wih0[jc*3+k],     Wih0[(3+jc)*3+k] };
      wgo[k]   = (v2f){ Wih0[(6+jc)*3+k], Wih0[(9+jc)*3+k] };
      wif[3+k] = (v2f){ 0.f, 0.f };
      wgo[3+k] = (v2f){ 0.f, 0.f };
      wif[6+k] = (v2f){ Whh0[jc*3+k],     Whh0[(3+jc)*3+k] };
      wgo[6+k] = (v2f){ Whh0[(6+jc)*3+k], Whh0[(9+jc)*3+k] };
    }
    bif = (v2f){ bih0[jc]+bhh0[jc],     bih0[3+jc]+bhh0[3+jc] };
    bgo = (v2f){ bih0[6+jc]+bhh0[6+jc], bih0[9+jc]+bhh0[9+jc] };
  } else {
#pragma unroll
    for (int k = 0; k < 6; ++k) {
      wif[k] = (v2f){ Wih1[jc*6+k],     Wih1[(3+jc)*6+k] };
      wgo[k] = (v2f){ Wih1[(6+jc)*6+k], Wih1[(9+jc)*6+k] };
    }
#pragma unroll
    for (int k = 0; k < 3; ++k) {
      wif[6+k] = (v2f){ Whh1[jc*3+k],     Whh1[(3+jc)*3+k] };
      wgo[6+k] = (v2f){ Whh1[(6+jc)*3+k], Whh1[(9+jc)*3+k] };
    }
    bif = (v2f){ bih1[jc]+bhh1[jc],     bih1[3+jc]+bhh1[3+jc] };
    bgo = (v2f){ bih1[6+jc]+bhh1[6+jc], bih1[9+jc]+bhh1[9+jc] };
  }

  float h = 0.f, c = 0.f;
  float ha0 = 0.f, ha1 = 0.f, ha2 = 0.f;  // role-own h(t-1)
  float hb0 = 0.f, hb1 = 0.f, hb2 = 0.f;  // layer-0 h (for role1)
  const float4* baseq =
      (const float4*)((role1 ? y0b : x) + (size_t)b * (T_ * 3));

  // y0b slot 0 = h_bwd(T-1): input of l1-fwd final step AND 1-step l1-bwd.
  const float* up = y0b + (size_t)b * (T_ * 3);
  float ub0 = up[0], ub1 = up[1], ub2 = up[2];

  float4 A4[6], B4[6];
  auto LD = [&](int blk, float4* dst) {
#pragma unroll
    for (int k = 0; k < 6; ++k) dst[k] = baseq[blk * 6 + k];
    __builtin_amdgcn_sched_barrier(0);
  };
  auto STEP = [&](float L0, float L1, float L2, bool valid) {
    float v0 = role1 ? hb0 : L0;
    float v1 = role1 ? hb1 : L1;
    float v2 = role1 ? hb2 : L2;
    v2f aif = pkfma(wif[0], v0, bif);
    aif = pkfma(wif[1], v1, aif);
    aif = pkfma(wif[2], v2, aif);
    aif = pkfma(wif[3], L0, aif);
    aif = pkfma(wif[4], L1, aif);
    v2f uif = wif[5] * sp(L2);
    uif = pkfma(wif[6], ha0, uif);
    uif = pkfma(wif[7], ha1, uif);
    uif = pkfma(wif[8], ha2, uif);
    v2f pif = aif + uif;
    v2f ago = pkfma(wgo[0], v0, bgo);
    ago = pkfma(wgo[1], v1, ago);
    ago = pkfma(wgo[2], v2, ago);
    ago = pkfma(wgo[3], L0, ago);
    ago = pkfma(wgo[4], L1, ago);
    v2f ugo = wgo[5] * sp(L2);
    ugo = pkfma(wgo[6], ha0, ugo);
    ugo = pkfma(wgo[7], ha1, ugo);
    ugo = pkfma(wgo[8], ha2, ugo);
    v2f pgo = ago + ugo;

    v2f eif = pif * sp(-LOG2E);
    float ig = rcp_(1.f + exp2_(eif.x));
    float fg = rcp_(1.f + exp2_(eif.y));
    float gg = tanh_(pgo.x);
    float og = sigm_(pgo.y);
    float cn = fg * c + ig * gg;
    float hn = og * tanh_(cn);
    c = valid ? cn : c;
    h = valid ? hn : h;
    ha0 = dppf<QB0>(h); ha1 = dppf<QB1>(h); ha2 = dppf<QB2>(h);
    hb0 = dppf<SHR4>(ha0); hb1 = dppf<SHR4>(ha1); hb2 = dppf<SHR4>(ha2);
  };
  auto PROC = [&](int blk, const float4* v) {
#pragma unroll
    for (int s = 0; s < 8; ++s) {
      int tt = blk * 8 + s;
      bool valid = role1 ? (tt != 0) : true;   // role1 lags: processes t=tt-1
      STEP(el(v,s*3), el(v,s*3+1), el(v,s*3+2), valid);
    }
  };

  LD(0, A4); LD(1, B4);
  for (int blk = 0; blk < 64; blk += 2) {
    PROC(blk, A4);
    if (blk + 2 < 64) LD(blk + 2, A4);
    PROC(blk + 1, B4);
    if (blk + 3 < 64) LD(blk + 3, B4);
  }
  // Final step: l1 processes t=T-1, consuming hb (=h0_fwd(T-1)) and ub.
  STEP(ub0, ub1, ub2, role1);
  // role1 lanes 4-6: h = h1_fwd[j](T-1). ha(role0)/hb(role1) = h0_fwd(T-1).

  float e0 = role1 ? hb0 : ha0;
  float e1 = role1 ? hb1 : ha1;
  float e2 = role1 ? hb2 : ha2;

  // Layer-1 backward: one step from zero state (all lanes, own jc).
  float h1b;
  {
    float wr[4][6], br[4];
#pragma unroll
    for (int g = 0; g < 4; ++g) {
      int r = g * 3 + jc;
#pragma unroll
      for (int k = 0; k < 6; ++k) wr[g][k] = Wih1r[r*6+k];
      br[g] = bih1r[r] + bhh1r[r];
    }
    float q[4];
#pragma unroll
    for (int g = 0; g < 4; ++g)
      q[g] = br[g] + wr[g][0]*e0 + wr[g][1]*e1 + wr[g][2]*e2
                   + wr[g][3]*ub0 + wr[g][4]*ub1 + wr[g][5]*ub2;
    float ig = sigm_(q[0]), gg = tanh_(q[2]), og = sigm_(q[3]);
    h1b = og * tanh_(ig * gg);          // c_prev = 0 -> f-gate drops out
  }

  float part = 0.f;
  if (role1) { if (j < 3) part = Wlin[j]     * h;   }
  else       { if (j < 3) part = Wlin[3 + j] * h1b; }
  part += __shfl_xor(part, 1, 8);
  part += __shfl_xor(part, 2, 8);
  part += __shfl_xor(part, 4, 8);
  if (lane == 0) out[b] = sigm_(part + blin[0]);
}

extern "C" void kernel_launch(void* const* d_in, const int* in_sizes, int n_in,
                              void* d_out, int out_size, void* d_ws, size_t ws_size,
                              hipStream_t stream) {
  const float* x        = (const float*)d_in[0];
  const float* W_ih_l0  = (const float*)d_in[1];
  const float* W_hh_l0  = (const float*)d_in[2];
  const float* b_ih_l0  = (const float*)d_in[3];
  const float* b_hh_l0  = (const float*)d_in[4];
  const float* W_ih_l0r = (const float*)d_in[5];
  const float* W_hh_l0r = (const float*)d_in[6];
  const float* b_ih_l0r = (const float*)d_in[7];
  const float* b_hh_l0r = (const float*)d_in[8];
  const float* W_ih_l1  = (const float*)d_in[9];
  const float* W_hh_l1  = (const float*)d_in[10];
  const float* b_ih_l1  = (const float*)d_in[11];
  const float* b_hh_l1  = (const float*)d_in[12];
  const float* W_ih_l1r = (const float*)d_in[13];
  const float* W_hh_l1r = (const float*)d_in[14];
  const float* b_ih_l1r = (const float*)d_in[15];
  const float* b_hh_l1r = (const float*)d_in[16];
  const float* W_lin    = (const float*)d_in[17];
  const float* b_lin    = (const float*)d_in[18];

  float* y0b = (float*)d_ws;   // [B][T][3] fp32 = 48 MB, shifted layout
  float* out = (float*)d_out;

  lstm_l0_bwd<<<(B_ * 4) / 256, 256, 0, stream>>>(
      x, W_ih_l0r, W_hh_l0r, b_ih_l0r, b_hh_l0r, y0b);

  lstm_fused_fwd<<<(B_ * 8) / 256, 256, 0, stream>>>(
      x, W_ih_l0, W_hh_l0, b_ih_l0, b_hh_l0,
      W_ih_l1, W_hh_l1, b_ih_l1, b_hh_l1,
      W_ih_l1r, W_hh_l1r, b_ih_l1r, b_hh_l1r,
      W_lin, b_lin, y0b, out);
}

// Round 4
// 159.623 us; speedup vs baseline: 2.7121x; 1.0738x over previous
//
#include <hip/hip_runtime.h>

// Model_47510928228872: 2-layer bidirectional LSTM (H=3) + linear + sigmoid.
// B=8192, T=512, fp32.
//
// K1 (l0-bwd) was store-stalled: per-step scattered 12B stores (16 cache
// lines / instr) fill the vmcnt queue -> ~400 stall cy/step. Fix: workspace
// layout [B][64][3][8] (block-transposed, +1 time shift); lanes accumulate
// 8 h's in registers and flush 2 contiguous float4 stores per 8 steps.
// K2 reads the same 96B blocks (element permutation is compile-time).

#define B_ 8192
#define T_ 512
#define LOG2E 1.4426950408889634f

typedef float v2f __attribute__((ext_vector_type(2)));

__device__ __forceinline__ float rcp_(float x)  { return __builtin_amdgcn_rcpf(x); }
__device__ __forceinline__ float exp2_(float x) { return __builtin_amdgcn_exp2f(x); }
__device__ __forceinline__ float sigm_(float x) {
  return rcp_(1.0f + exp2_(-LOG2E * x));
}
__device__ __forceinline__ float tanh_(float x) {
  return 1.0f - 2.0f * rcp_(1.0f + exp2_(2.0f * LOG2E * x));
}
__device__ __forceinline__ v2f sp(float s) { return (v2f){s, s}; }
__device__ __forceinline__ v2f pkfma(v2f a, float b, v2f c) {
  return __builtin_elementwise_fma(a, sp(b), c);
}

template <int CTRL>
__device__ __forceinline__ float dppf(float v) {
  int s = __float_as_int(v);
  return __int_as_float(__builtin_amdgcn_update_dpp(s, s, CTRL, 0xF, 0xF, false));
}
#define QB0 0x00   // quad_perm broadcast lane0 of quad
#define QB1 0x55
#define QB2 0xAA
#define SHR4 0x114 // row_shr:4 (quad1 <- quad0)

// float4-array element access with compile-time index
__device__ __forceinline__ float el(const float4* a, int i) {
  const float4 v = a[i >> 2];
  const int r = i & 3;
  return r == 0 ? v.x : r == 1 ? v.y : r == 2 ? v.z : v.w;
}

// ---------------- Kernel 1: layer-0 backward ----------------
__global__ __launch_bounds__(256, 1) void lstm_l0_bwd(
    const float* __restrict__ x,      // [B][T][3]
    const float* __restrict__ Wih, const float* __restrict__ Whh,
    const float* __restrict__ bih, const float* __restrict__ bhh,
    float* __restrict__ y0b)          // [B][64][3][8], slot t+1 holds h_bwd(t)
{
  int tid = blockIdx.x * 256 + threadIdx.x;
  int b = tid >> 2, jl = tid & 3;
  int j = (jl < 3) ? jl : 0;          // lane 3 duplicates j=0 (never stored)

  v2f wif[6], wgo[6];
#pragma unroll
  for (int k = 0; k < 3; ++k) {
    wif[k]   = (v2f){ Wih[j*3+k],     Wih[(3+j)*3+k] };
    wif[3+k] = (v2f){ Whh[j*3+k],     Whh[(3+j)*3+k] };
    wgo[k]   = (v2f){ Wih[(6+j)*3+k], Wih[(9+j)*3+k] };
    wgo[3+k] = (v2f){ Whh[(6+j)*3+k], Whh[(9+j)*3+k] };
  }
  v2f bif = (v2f){ bih[j]+bhh[j],     bih[3+j]+bhh[3+j] };
  v2f bgo = (v2f){ bih[6+j]+bhh[6+j], bih[9+j]+bhh[9+j] };

  float h = 0.f, c = 0.f, hb0 = 0.f, hb1 = 0.f, hb2 = 0.f;
  const float4* xq = (const float4*)(x + (size_t)b * (T_ * 3));
  float* ywb = y0b + (size_t)b * (T_ * 3) + jl * 8;   // lane's j-plane base

  float hst[8];      // h for slots 0..7 of the pending y-block (compile-time idx)
  float h511 = 0.f;  // h_bwd(T-1) -> y-block 0 slot 0, flushed at the very end

  float4 A4[6], B4[6];
  auto LD = [&](int blk, float4* dst) {
#pragma unroll
    for (int k = 0; k < 6; ++k) dst[k] = xq[blk * 6 + k];
    __builtin_amdgcn_sched_barrier(0);   // pin prefetch issue point
  };
  auto STEP = [&](float x0, float x1, float x2, int slot) {
    v2f aif = pkfma(wif[0], x0, bif);
    aif = pkfma(wif[1], x1, aif);
    aif = pkfma(wif[2], x2, aif);
    v2f uif = wif[3] * sp(hb0);
    uif = pkfma(wif[4], hb1, uif);
    uif = pkfma(wif[5], hb2, uif);
    v2f pif = aif + uif;
    v2f ago = pkfma(wgo[0], x0, bgo);
    ago = pkfma(wgo[1], x1, ago);
    ago = pkfma(wgo[2], x2, ago);
    v2f ugo = wgo[3] * sp(hb0);
    ugo = pkfma(wgo[4], hb1, ugo);
    ugo = pkfma(wgo[5], hb2, ugo);
    v2f pgo = ago + ugo;

    v2f eif = pif * sp(-LOG2E);
    float ig = rcp_(1.f + exp2_(eif.x));
    float fg = rcp_(1.f + exp2_(eif.y));
    float gg = tanh_(pgo.x);
    float og = sigm_(pgo.y);
    c = fg * c + ig * gg;
    h = og * tanh_(c);
    hb0 = dppf<QB0>(h); hb1 = dppf<QB1>(h); hb2 = dppf<QB2>(h);
    hst[slot] = h;
  };
  auto FLUSH = [&](int yblk) {
    if (jl < 3) {
      float4* p = (float4*)(ywb + yblk * 24);
      p[0] = make_float4(hst[0], hst[1], hst[2], hst[3]);
      p[1] = make_float4(hst[4], hst[5], hst[6], hst[7]);
    }
  };
  // Process x-block blk: t = blk*8+7 .. blk*8. Slot of t is (t+1)&7.
  // After the first step (slot 0), y-block blk+1 is complete -> flush
  // (except the very first x-block, whose slot-0 value is h_bwd(T-1)).
  auto PROC = [&](int blk, const float4* v, bool first) {
    STEP(el(v,21), el(v,22), el(v,23), 0);
    if (first) h511 = hst[0]; else FLUSH(blk + 1);
#pragma unroll
    for (int sx = 6; sx >= 0; --sx)
      STEP(el(v,sx*3), el(v,sx*3+1), el(v,sx*3+2), sx + 1);
  };

  LD(63, A4); LD(62, B4);
  PROC(63, A4, true);  LD(61, A4);
  PROC(62, B4, false); LD(60, B4);
  for (int blk = 61; blk >= 1; blk -= 2) {
    PROC(blk, A4, false);
    if (blk >= 3) LD(blk - 2, A4);
    PROC(blk - 1, B4, false);
    if (blk >= 3) LD(blk - 3, B4);
  }
  hst[0] = h511;
  FLUSH(0);
}

// ---------------- Kernel 2: l0-fwd + l1-fwd fused + epilogue ----------------
__global__ __launch_bounds__(256, 1) void lstm_fused_fwd(
    const float* __restrict__ x,
    const float* __restrict__ Wih0, const float* __restrict__ Whh0,
    const float* __restrict__ bih0, const float* __restrict__ bhh0,
    const float* __restrict__ Wih1, const float* __restrict__ Whh1,
    const float* __restrict__ bih1, const float* __restrict__ bhh1,
    const float* __restrict__ Wih1r, const float* __restrict__ Whh1r,
    const float* __restrict__ bih1r, const float* __restrict__ bhh1r,
    const float* __restrict__ Wlin, const float* __restrict__ blin,
    const float* __restrict__ y0b,   // [B][64][3][8] shifted
    float* __restrict__ out)         // [B]
{
  int tid = blockIdx.x * 256 + threadIdx.x;
  int b = tid >> 3, lane = tid & 7;
  bool role1 = lane >= 4;               // quad 1 = layer-1 cell
  int j  = role1 ? (lane - 4) : lane;
  int jc = (j < 3) ? j : 2;

  v2f wif[9], wgo[9];
  v2f bif, bgo;
  if (!role1) {
#pragma unroll
    for (int k = 0; k < 3; ++k) {
      wif[k]   = (v2f){ Wih0[jc*3+k],     Wih0[(3+jc)*3+k] };
      wgo[k]   = (v2f){ Wih0[(6+jc)*3+k], Wih0[(9+jc)*3+k] };
      wif[3+k] = (v2f){ 0.f, 0.f };
      wgo[3+k] = (v2f){ 0.f, 0.f };
      wif[6+k] = (v2f){ Whh0[jc*3+k],     Whh0[(3+jc)*3+k] };
      wgo[6+k] = (v2f){ Whh0[(6+jc)*3+k], Whh0[(9+jc)*3+k] };
    }
    bif = (v2f){ bih0[jc]+bhh0[jc],     bih0[3+jc]+bhh0[3+jc] };
    bgo = (v2f){ bih0[6+jc]+bhh0[6+jc], bih0[9+jc]+bhh0[9+jc] };
  } else {
#pragma unroll
    for (int k = 0; k < 6; ++k) {
      wif[k] = (v2f){ Wih1[jc*6+k],     Wih1[(3+jc)*6+k] };
      wgo[k] = (v2f){ Wih1[(6+jc)*6+k], Wih1[(9+jc)*6+k] };
    }
#pragma unroll
    for (int k = 0; k < 3; ++k) {
      wif[6+k] = (v2f){ Whh1[jc*3+k],     Whh1[(3+jc)*3+k] };
      wgo[6+k] = (v2f){ Whh1[(6+jc)*3+k], Whh1[(9+jc)*3+k] };
    }
    bif = (v2f){ bih1[jc]+bhh1[jc],     bih1[3+jc]+bhh1[3+jc] };
    bgo = (v2f){ bih1[6+jc]+bhh1[6+jc], bih1[9+jc]+bhh1[9+jc] };
  }

  float h = 0.f, c = 0.f;
  float ha0 = 0.f, ha1 = 0.f, ha2 = 0.f;  // role-own h(t-1)
  float hb0 = 0.f, hb1 = 0.f, hb2 = 0.f;  // layer-0 h (for role1)
  const float4* baseq =
      (const float4*)((role1 ? y0b : x) + (size_t)b * (T_ * 3));

  // y0b block 0, slot 0 = h_bwd(T-1)[j] at offset j*8.
  const float* up = y0b + (size_t)b * (T_ * 3);
  float ub0 = up[0], ub1 = up[8], ub2 = up[16];

  float4 A4[6], B4[6];
  auto LD = [&](int blk, float4* dst) {
#pragma unroll
    for (int k = 0; k < 6; ++k) dst[k] = baseq[blk * 6 + k];
    __builtin_amdgcn_sched_barrier(0);
  };
  auto STEP = [&](float L0, float L1, float L2, bool valid) {
    float v0 = role1 ? hb0 : L0;
    float v1 = role1 ? hb1 : L1;
    float v2 = role1 ? hb2 : L2;
    v2f aif = pkfma(wif[0], v0, bif);
    aif = pkfma(wif[1], v1, aif);
    aif = pkfma(wif[2], v2, aif);
    aif = pkfma(wif[3], L0, aif);
    aif = pkfma(wif[4], L1, aif);
    v2f uif = wif[5] * sp(L2);
    uif = pkfma(wif[6], ha0, uif);
    uif = pkfma(wif[7], ha1, uif);
    uif = pkfma(wif[8], ha2, uif);
    v2f pif = aif + uif;
    v2f ago = pkfma(wgo[0], v0, bgo);
    ago = pkfma(wgo[1], v1, ago);
    ago = pkfma(wgo[2], v2, ago);
    ago = pkfma(wgo[3], L0, ago);
    ago = pkfma(wgo[4], L1, ago);
    v2f ugo = wgo[5] * sp(L2);
    ugo = pkfma(wgo[6], ha0, ugo);
    ugo = pkfma(wgo[7], ha1, ugo);
    ugo = pkfma(wgo[8], ha2, ugo);
    v2f pgo = ago + ugo;

    v2f eif = pif * sp(-LOG2E);
    float ig = rcp_(1.f + exp2_(eif.x));
    float fg = rcp_(1.f + exp2_(eif.y));
    float gg = tanh_(pgo.x);
    float og = sigm_(pgo.y);
    float cn = fg * c + ig * gg;
    float hn = og * tanh_(cn);
    c = valid ? cn : c;
    h = valid ? hn : h;
    ha0 = dppf<QB0>(h); ha1 = dppf<QB1>(h); ha2 = dppf<QB2>(h);
    hb0 = dppf<SHR4>(ha0); hb1 = dppf<SHR4>(ha1); hb2 = dppf<SHR4>(ha2);
  };
  auto PROC = [&](int blk, const float4* v) {
#pragma unroll
    for (int s = 0; s < 8; ++s) {
      int tt = blk * 8 + s;
      // role0 reads x as [8 t][3 k]; role1 reads y0b block as [3 j][8 s].
      float L0 = role1 ? el(v, 0*8 + s) : el(v, s*3 + 0);
      float L1 = role1 ? el(v, 1*8 + s) : el(v, s*3 + 1);
      float L2 = role1 ? el(v, 2*8 + s) : el(v, s*3 + 2);
      bool valid = role1 ? (tt != 0) : true;   // role1 lags one step
      STEP(L0, L1, L2, valid);
    }
  };

  LD(0, A4); LD(1, B4);
  for (int blk = 0; blk < 64; blk += 2) {
    PROC(blk, A4);
    if (blk + 2 < 64) LD(blk + 2, A4);
    PROC(blk + 1, B4);
    if (blk + 3 < 64) LD(blk + 3, B4);
  }
  // Final step: l1 processes t=T-1, consuming hb (=h0_fwd(T-1)) and ub.
  STEP(ub0, ub1, ub2, role1);
  // role1 lanes 4-6: h = h1_fwd[j](T-1). ha(role0)/hb(role1) = h0_fwd(T-1).

  float e0 = role1 ? hb0 : ha0;
  float e1 = role1 ? hb1 : ha1;
  float e2 = role1 ? hb2 : ha2;

  // Layer-1 backward: one step from zero state (all lanes, own jc).
  float h1b;
  {
    float wr[4][6], br[4];
#pragma unroll
    for (int g = 0; g < 4; ++g) {
      int r = g * 3 + jc;
#pragma unroll
      for (int k = 0; k < 6; ++k) wr[g][k] = Wih1r[r*6+k];
      br[g] = bih1r[r] + bhh1r[r];
    }
    float q[4];
#pragma unroll
    for (int g = 0; g < 4; ++g)
      q[g] = br[g] + wr[g][0]*e0 + wr[g][1]*e1 + wr[g][2]*e2
                   + wr[g][3]*ub0 + wr[g][4]*ub1 + wr[g][5]*ub2;
    float ig = sigm_(q[0]), gg = tanh_(q[2]), og = sigm_(q[3]);
    h1b = og * tanh_(ig * gg);          // c_prev = 0 -> f-gate drops out
  }

  float part = 0.f;
  if (role1) { if (j < 3) part = Wlin[j]     * h;   }
  else       { if (j < 3) part = Wlin[3 + j] * h1b; }
  part += __shfl_xor(part, 1, 8);
  part += __shfl_xor(part, 2, 8);
  part += __shfl_xor(part, 4, 8);
  if (lane == 0) out[b] = sigm_(part + blin[0]);
}

extern "C" void kernel_launch(void* const* d_in, const int* in_sizes, int n_in,
                              void* d_out, int out_size, void* d_ws, size_t ws_size,
                              hipStream_t stream) {
  const float* x        = (const float*)d_in[0];
  const float* W_ih_l0  = (const float*)d_in[1];
  const float* W_hh_l0  = (const float*)d_in[2];
  const float* b_ih_l0  = (const float*)d_in[3];
  const float* b_hh_l0  = (const float*)d_in[4];
  const float* W_ih_l0r = (const float*)d_in[5];
  const float* W_hh_l0r = (const float*)d_in[6];
  const float* b_ih_l0r = (const float*)d_in[7];
  const float* b_hh_l0r = (const float*)d_in[8];
  const float* W_ih_l1  = (const float*)d_in[9];
  const float* W_hh_l1  = (const float*)d_in[10];
  const float* b_ih_l1  = (const float*)d_in[11];
  const float* b_hh_l1  = (const float*)d_in[12];
  const float* W_ih_l1r = (const float*)d_in[13];
  const float* W_hh_l1r = (const float*)d_in[14];
  const float* b_ih_l1r = (const float*)d_in[15];
  const float* b_hh_l1r = (const float*)d_in[16];
  const float* W_lin    = (const float*)d_in[17];
  const float* b_lin    = (const float*)d_in[18];

  float* y0b = (float*)d_ws;   // [B][64][3][8] fp32 = 48 MB, shifted layout
  float* out = (float*)d_out;

  lstm_l0_bwd<<<(B_ * 4) / 256, 256, 0, stream>>>(
      x, W_ih_l0r, W_hh_l0r, b_ih_l0r, b_hh_l0r, y0b);

  lstm_fused_fwd<<<(B_ * 8) / 256, 256, 0, stream>>>(
      x, W_ih_l0, W_hh_l0, b_ih_l0, b_hh_l0,
      W_ih_l1, W_hh_l1, b_ih_l1, b_hh_l1,
      W_ih_l1r, W_hh_l1r, b_ih_l1r, b_hh_l1r,
      W_lin, b_lin, y0b, out);
}

// Round 5
// 151.876 us; speedup vs baseline: 2.8504x; 1.0510x over previous
//
#include <hip/hip_runtime.h>

// Model_47510928228872: 2-layer bidirectional LSTM (H=3) + linear + sigmoid.
// B=8192, T=512, fp32.
//
// Round-5 fix: previous rounds' prefetch buffers were ADDRESS-TAKEN arrays
// (passed by pointer into lambdas) -> SROA failed -> buffers lived in scratch
// (VGPR_Count 52/64 << ~105 live values). All hot-loop state is now named
// float4/v2f variables accessed via macros. Same algorithm:
//  K1: l0-bwd, 4 lanes/batch, ws layout [B][64][3 j][8 s] (+1 time shift),
//      register-accumulated block stores (2x float4 per 8 steps).
//  K2: l0-fwd (quad0) + l1-fwd (quad1, lags 1 step) fused, DPP h-exchange,
//      1-step l1-bwd epilogue + linear + sigmoid.

#define B_ 8192
#define T_ 512
#define LOG2E 1.4426950408889634f

typedef float v2f __attribute__((ext_vector_type(2)));

__device__ __forceinline__ float rcp_(float x)  { return __builtin_amdgcn_rcpf(x); }
__device__ __forceinline__ float exp2_(float x) { return __builtin_amdgcn_exp2f(x); }
__device__ __forceinline__ float sigm_(float x) {
  return rcp_(1.0f + exp2_(-LOG2E * x));
}
__device__ __forceinline__ float tanh_(float x) {
  return 1.0f - 2.0f * rcp_(1.0f + exp2_(2.0f * LOG2E * x));
}
__device__ __forceinline__ v2f sp(float s) { return (v2f){s, s}; }
__device__ __forceinline__ v2f pkfma(v2f a, float b, v2f c) {
  return __builtin_elementwise_fma(a, sp(b), c);
}

template <int CTRL>
__device__ __forceinline__ float dppf(float v) {
  int s = __float_as_int(v);
  return __int_as_float(__builtin_amdgcn_update_dpp(s, s, CTRL, 0xF, 0xF, false));
}
#define QB0 0x00   // quad_perm broadcast lane0 of quad
#define QB1 0x55
#define QB2 0xAA
#define SHR4 0x114 // row_shr:4 (quad1 <- quad0)

// ---------------- Kernel 1: layer-0 backward ----------------
__global__ __launch_bounds__(256, 1) void lstm_l0_bwd(
    const float* __restrict__ x,      // [B][T][3]
    const float* __restrict__ Wih, const float* __restrict__ Whh,
    const float* __restrict__ bih, const float* __restrict__ bhh,
    float* __restrict__ y0b)          // [B][64][3][8], slot t+1 holds h_bwd(t)
{
  int tid = blockIdx.x * 256 + threadIdx.x;
  int b = tid >> 2, jl = tid & 3;
  int j = (jl < 3) ? jl : 0;          // lane 3 duplicates j=0 (never stored)
  const int r0 = j, r1 = 3 + j, r2 = 6 + j, r3 = 9 + j;

  v2f wif0 = {Wih[r0*3+0], Wih[r1*3+0]}, wif1 = {Wih[r0*3+1], Wih[r1*3+1]},
      wif2 = {Wih[r0*3+2], Wih[r1*3+2]};
  v2f wif3 = {Whh[r0*3+0], Whh[r1*3+0]}, wif4 = {Whh[r0*3+1], Whh[r1*3+1]},
      wif5 = {Whh[r0*3+2], Whh[r1*3+2]};
  v2f wgo0 = {Wih[r2*3+0], Wih[r3*3+0]}, wgo1 = {Wih[r2*3+1], Wih[r3*3+1]},
      wgo2 = {Wih[r2*3+2], Wih[r3*3+2]};
  v2f wgo3 = {Whh[r2*3+0], Whh[r3*3+0]}, wgo4 = {Whh[r2*3+1], Whh[r3*3+1]},
      wgo5 = {Whh[r2*3+2], Whh[r3*3+2]};
  v2f bif = {bih[r0]+bhh[r0], bih[r1]+bhh[r1]};
  v2f bgo = {bih[r2]+bhh[r2], bih[r3]+bhh[r3]};

  float h = 0.f, c = 0.f, hb0 = 0.f, hb1 = 0.f, hb2 = 0.f;
  const float4* xq = (const float4*)(x + (size_t)b * (T_ * 3));
  float* ywb = y0b + (size_t)b * (T_ * 3) + jl * 8;   // lane's j-plane base

  float hs0 = 0.f, hs1 = 0.f, hs2 = 0.f, hs3 = 0.f,
        hs4 = 0.f, hs5 = 0.f, hs6 = 0.f, hs7 = 0.f, h511 = 0.f;
  float4 p0, p1, p2, p3, p4, p5, q0, q1, q2, q3, q4, q5;

#define LD1(blk, r0_, r1_, r2_, r3_, r4_, r5_) do {                       \
    const float4* _p = xq + (blk) * 6;                                    \
    r0_ = _p[0]; r1_ = _p[1]; r2_ = _p[2];                                \
    r3_ = _p[3]; r4_ = _p[4]; r5_ = _p[5];                                \
    __builtin_amdgcn_sched_barrier(0); } while (0)

#define STEP1(x0, x1, x2, HOUT) do {                                      \
    v2f aif = pkfma(wif0, (x0), bif); aif = pkfma(wif1, (x1), aif);       \
    aif = pkfma(wif2, (x2), aif);                                         \
    v2f uif = wif3 * sp(hb0); uif = pkfma(wif4, hb1, uif);                \
    uif = pkfma(wif5, hb2, uif);                                          \
    v2f pif = aif + uif;                                                  \
    v2f ago = pkfma(wgo0, (x0), bgo); ago = pkfma(wgo1, (x1), ago);       \
    ago = pkfma(wgo2, (x2), ago);                                         \
    v2f ugo = wgo3 * sp(hb0); ugo = pkfma(wgo4, hb1, ugo);                \
    ugo = pkfma(wgo5, hb2, ugo);                                          \
    v2f pgo = ago + ugo;                                                  \
    v2f eif = pif * sp(-LOG2E);                                           \
    v2f ego = pgo * (v2f){2.f * LOG2E, -LOG2E};                           \
    float ig = rcp_(1.f + exp2_(eif.x));                                  \
    float fg = rcp_(1.f + exp2_(eif.y));                                  \
    float gg = 1.f - 2.f * rcp_(1.f + exp2_(ego.x));                      \
    float og = rcp_(1.f + exp2_(ego.y));                                  \
    c = fg * c + ig * gg;                                                 \
    h = og * tanh_(c);                                                    \
    hb0 = dppf<QB0>(h); hb1 = dppf<QB1>(h); hb2 = dppf<QB2>(h);           \
    HOUT = h; } while (0)

#define FLUSH1(yblk) do {                                                 \
    if (jl < 3) {                                                         \
      float4* _o = (float4*)(ywb + (yblk) * 24);                          \
      _o[0] = make_float4(hs0, hs1, hs2, hs3);                            \
      _o[1] = make_float4(hs4, hs5, hs6, hs7);                            \
    } } while (0)

  // Process x-block blk (t = blk*8+7 .. blk*8, descending). Slot of t is
  // (t+1)&7; after the first step (slot 0) y-block blk+1 is complete.
#define PROC1(blk, r0_, r1_, r2_, r3_, r4_, r5_, FIRST) do {              \
    STEP1(r5_.y, r5_.z, r5_.w, hs0);                                      \
    if (FIRST) h511 = hs0; else FLUSH1((blk) + 1);                        \
    STEP1(r4_.z, r4_.w, r5_.x, hs7);                                      \
    STEP1(r3_.w, r4_.x, r4_.y, hs6);                                      \
    STEP1(r3_.x, r3_.y, r3_.z, hs5);                                      \
    STEP1(r2_.y, r2_.z, r2_.w, hs4);                                      \
    STEP1(r1_.z, r1_.w, r2_.x, hs3);                                      \
    STEP1(r0_.w, r1_.x, r1_.y, hs2);                                      \
    STEP1(r0_.x, r0_.y, r0_.z, hs1); } while (0)

  LD1(63, p0, p1, p2, p3, p4, p5);
  LD1(62, q0, q1, q2, q3, q4, q5);
  PROC1(63, p0, p1, p2, p3, p4, p5, true);
  LD1(61, p0, p1, p2, p3, p4, p5);
  PROC1(62, q0, q1, q2, q3, q4, q5, false);
  LD1(60, q0, q1, q2, q3, q4, q5);
  for (int blk = 61; blk >= 1; blk -= 2) {
    PROC1(blk, p0, p1, p2, p3, p4, p5, false);
    if (blk >= 3) LD1(blk - 2, p0, p1, p2, p3, p4, p5);
    PROC1(blk - 1, q0, q1, q2, q3, q4, q5, false);
    if (blk >= 3) LD1(blk - 3, q0, q1, q2, q3, q4, q5);
  }
  hs0 = h511;
  FLUSH1(0);
#undef LD1
#undef STEP1
#undef FLUSH1
#undef PROC1
}

// ---------------- Kernel 2: l0-fwd + l1-fwd fused + epilogue ----------------
__global__ __launch_bounds__(256, 1) void lstm_fused_fwd(
    const float* __restrict__ x,
    const float* __restrict__ Wih0, const float* __restrict__ Whh0,
    const float* __restrict__ bih0, const float* __restrict__ bhh0,
    const float* __restrict__ Wih1, const float* __restrict__ Whh1,
    const float* __restrict__ bih1, const float* __restrict__ bhh1,
    const float* __restrict__ Wih1r, const float* __restrict__ Whh1r,
    const float* __restrict__ bih1r, const float* __restrict__ bhh1r,
    const float* __restrict__ Wlin, const float* __restrict__ blin,
    const float* __restrict__ y0b,   // [B][64][3][8] shifted
    float* __restrict__ out)         // [B]
{
  int tid = blockIdx.x * 256 + threadIdx.x;
  int b = tid >> 3, lane = tid & 7;
  bool role1 = lane >= 4;               // quad 1 = layer-1 cell
  int j  = role1 ? (lane - 4) : lane;
  int jc = (j < 3) ? j : 2;
  const int r0 = jc, r1 = 3 + jc, r2 = 6 + jc, r3 = 9 + jc;

  // Unified 9-input packed cell: m0..m2 (role0 x / selected), n0..n2 (role1's
  // own-layout load; role0 weights for these columns are zero), ha0..ha2.
  v2f wif0, wif1, wif2, wif3, wif4, wif5, wif6, wif7, wif8;
  v2f wgo0, wgo1, wgo2, wgo3, wgo4, wgo5, wgo6, wgo7, wgo8;
  v2f bif, bgo;
  if (!role1) {
    wif0 = (v2f){Wih0[r0*3+0], Wih0[r1*3+0]};
    wif1 = (v2f){Wih0[r0*3+1], Wih0[r1*3+1]};
    wif2 = (v2f){Wih0[r0*3+2], Wih0[r1*3+2]};
    wif3 = (v2f){0.f, 0.f}; wif4 = (v2f){0.f, 0.f}; wif5 = (v2f){0.f, 0.f};
    wif6 = (v2f){Whh0[r0*3+0], Whh0[r1*3+0]};
    wif7 = (v2f){Whh0[r0*3+1], Whh0[r1*3+1]};
    wif8 = (v2f){Whh0[r0*3+2], Whh0[r1*3+2]};
    wgo0 = (v2f){Wih0[r2*3+0], Wih0[r3*3+0]};
    wgo1 = (v2f){Wih0[r2*3+1], Wih0[r3*3+1]};
    wgo2 = (v2f){Wih0[r2*3+2], Wih0[r3*3+2]};
    wgo3 = (v2f){0.f, 0.f}; wgo4 = (v2f){0.f, 0.f}; wgo5 = (v2f){0.f, 0.f};
    wgo6 = (v2f){Whh0[r2*3+0], Whh0[r3*3+0]};
    wgo7 = (v2f){Whh0[r2*3+1], Whh0[r3*3+1]};
    wgo8 = (v2f){Whh0[r2*3+2], Whh0[r3*3+2]};
    bif = (v2f){bih0[r0]+bhh0[r0], bih0[r1]+bhh0[r1]};
    bgo = (v2f){bih0[r2]+bhh0[r2], bih0[r3]+bhh0[r3]};
  } else {
    wif0 = (v2f){Wih1[r0*6+0], Wih1[r1*6+0]};
    wif1 = (v2f){Wih1[r0*6+1], Wih1[r1*6+1]};
    wif2 = (v2f){Wih1[r0*6+2], Wih1[r1*6+2]};
    wif3 = (v2f){Wih1[r0*6+3], Wih1[r1*6+3]};
    wif4 = (v2f){Wih1[r0*6+4], Wih1[r1*6+4]};
    wif5 = (v2f){Wih1[r0*6+5], Wih1[r1*6+5]};
    wif6 = (v2f){Whh1[r0*3+0], Whh1[r1*3+0]};
    wif7 = (v2f){Whh1[r0*3+1], Whh1[r1*3+1]};
    wif8 = (v2f){Whh1[r0*3+2], Whh1[r1*3+2]};
    wgo0 = (v2f){Wih1[r2*6+0], Wih1[r3*6+0]};
    wgo1 = (v2f){Wih1[r2*6+1], Wih1[r3*6+1]};
    wgo2 = (v2f){Wih1[r2*6+2], Wih1[r3*6+2]};
    wgo3 = (v2f){Wih1[r2*6+3], Wih1[r3*6+3]};
    wgo4 = (v2f){Wih1[r2*6+4], Wih1[r3*6+4]};
    wgo5 = (v2f){Wih1[r2*6+5], Wih1[r3*6+5]};
    wgo6 = (v2f){Whh1[r2*3+0], Whh1[r3*3+0]};
    wgo7 = (v2f){Whh1[r2*3+1], Whh1[r3*3+1]};
    wgo8 = (v2f){Whh1[r2*3+2], Whh1[r3*3+2]};
    bif = (v2f){bih1[r0]+bhh1[r0], bih1[r1]+bhh1[r1]};
    bgo = (v2f){bih1[r2]+bhh1[r2], bih1[r3]+bhh1[r3]};
  }

  float h = 0.f, c = 0.f;
  float ha0 = 0.f, ha1 = 0.f, ha2 = 0.f;  // role-own h(t-1)
  float hb0 = 0.f, hb1 = 0.f, hb2 = 0.f;  // layer-0 h (for role1)
  const float4* baseq =
      (const float4*)((role1 ? y0b : x) + (size_t)b * (T_ * 3));

  // y0b block 0, slot 0 = h_bwd(T-1)[j] at offset j*8.
  const float* up = y0b + (size_t)b * (T_ * 3);
  float ub0 = up[0], ub1 = up[8], ub2 = up[16];

  float4 p0, p1, p2, p3, p4, p5, q0, q1, q2, q3, q4, q5;

#define LD2(blk, r0_, r1_, r2_, r3_, r4_, r5_) do {                       \
    const float4* _p = baseq + (blk) * 6;                                 \
    r0_ = _p[0]; r1_ = _p[1]; r2_ = _p[2];                                \
    r3_ = _p[3]; r4_ = _p[4]; r5_ = _p[5];                                \
    __builtin_amdgcn_sched_barrier(0); } while (0)

  // Gate body shared by plain/valid variants. Defines cn,hn from inputs.
#define GATES2(m0, m1, m2, n0, n1, n2) /* -> cn, hn */                    \
    float v0 = role1 ? hb0 : (m0);                                        \
    float v1 = role1 ? hb1 : (m1);                                        \
    float v2 = role1 ? hb2 : (m2);                                        \
    v2f aif = pkfma(wif0, v0, bif); aif = pkfma(wif1, v1, aif);           \
    aif = pkfma(wif2, v2, aif);                                           \
    aif = pkfma(wif3, (n0), aif); aif = pkfma(wif4, (n1), aif);           \
    v2f uif = wif5 * sp(n2); uif = pkfma(wif6, ha0, uif);                 \
    uif = pkfma(wif7, ha1, uif); uif = pkfma(wif8, ha2, uif);             \
    v2f pif = aif + uif;                                                  \
    v2f ago = pkfma(wgo0, v0, bgo); ago = pkfma(wgo1, v1, ago);           \
    ago = pkfma(wgo2, v2, ago);                                           \
    ago = pkfma(wgo3, (n0), ago); ago = pkfma(wgo4, (n1), ago);           \
    v2f ugo = wgo5 * sp(n2); ugo = pkfma(wgo6, ha0, ugo);                 \
    ugo = pkfma(wgo7, ha1, ugo); ugo = pkfma(wgo8, ha2, ugo);             \
    v2f pgo = ago + ugo;                                                  \
    v2f eif = pif * sp(-LOG2E);                                           \
    v2f ego = pgo * (v2f){2.f * LOG2E, -LOG2E};                           \
    float ig = rcp_(1.f + exp2_(eif.x));                                  \
    float fg = rcp_(1.f + exp2_(eif.y));                                  \
    float gg = 1.f - 2.f * rcp_(1.f + exp2_(ego.x));                      \
    float og = rcp_(1.f + exp2_(ego.y));                                  \
    float cn = fg * c + ig * gg;                                          \
    float hn = og * tanh_(cn);

#define BCAST2() do {                                                     \
    ha0 = dppf<QB0>(h); ha1 = dppf<QB1>(h); ha2 = dppf<QB2>(h);           \
    hb0 = dppf<SHR4>(ha0); hb1 = dppf<SHR4>(ha1); hb2 = dppf<SHR4>(ha2);  \
  } while (0)

#define STEP2(m0, m1, m2, n0, n1, n2) do {                                \
    GATES2(m0, m1, m2, n0, n1, n2)                                        \
    c = cn; h = hn;                                                       \
    BCAST2(); } while (0)

#define STEP2V(m0, m1, m2, n0, n1, n2, VALID) do {                        \
    GATES2(m0, m1, m2, n0, n1, n2)                                        \
    c = (VALID) ? cn : c; h = (VALID) ? hn : h;                           \
    BCAST2(); } while (0)

  // role0 reads its block as [8 s][3 k]; role1 as [3 j][8 s].
#define PROC2(r0_, r1_, r2_, r3_, r4_, r5_) do {                          \
    STEP2(r0_.x, r0_.y, r0_.z,  r0_.x, r2_.x, r4_.x);                     \
    STEP2(r0_.w, r1_.x, r1_.y,  r0_.y, r2_.y, r4_.y);                     \
    STEP2(r1_.z, r1_.w, r2_.x,  r0_.z, r2_.z, r4_.z);                     \
    STEP2(r2_.y, r2_.z, r2_.w,  r0_.w, r2_.w, r4_.w);                     \
    STEP2(r3_.x, r3_.y, r3_.z,  r1_.x, r3_.x, r5_.x);                     \
    STEP2(r3_.w, r4_.x, r4_.y,  r1_.y, r3_.y, r5_.y);                     \
    STEP2(r4_.z, r4_.w, r5_.x,  r1_.z, r3_.z, r5_.z);                     \
    STEP2(r5_.y, r5_.z, r5_.w,  r1_.w, r3_.w, r5_.w); } while (0)

  LD2(0, p0, p1, p2, p3, p4, p5);
  LD2(1, q0, q1, q2, q3, q4, q5);
  // Block 0 peeled: step tt=0 is invalid for role1 (it lags one step).
  STEP2V(p0.x, p0.y, p0.z,  p0.x, p2.x, p4.x, !role1);
  STEP2(p0.w, p1.x, p1.y,  p0.y, p2.y, p4.y);
  STEP2(p1.z, p1.w, p2.x,  p0.z, p2.z, p4.z);
  STEP2(p2.y, p2.z, p2.w,  p0.w, p2.w, p4.w);
  STEP2(p3.x, p3.y, p3.z,  p1.x, p3.x, p5.x);
  STEP2(p3.w, p4.x, p4.y,  p1.y, p3.y, p5.y);
  STEP2(p4.z, p4.w, p5.x,  p1.z, p3.z, p5.z);
  STEP2(p5.y, p5.z, p5.w,  p1.w, p3.w, p5.w);
  LD2(2, p0, p1, p2, p3, p4, p5);
  PROC2(q0, q1, q2, q3, q4, q5);
  LD2(3, q0, q1, q2, q3, q4, q5);
  for (int blk = 2; blk < 64; blk += 2) {
    PROC2(p0, p1, p2, p3, p4, p5);
    if (blk + 2 < 64) LD2(blk + 2, p0, p1, p2, p3, p4, p5);
    PROC2(q0, q1, q2, q3, q4, q5);
    if (blk + 3 < 64) LD2(blk + 3, q0, q1, q2, q3, q4, q5);
  }
  // Final step tt=512: l1 processes t=T-1 consuming hb(=h0f(T-1)) and ub;
  // role0 must not update (h keeps h0f(T-1)).
  STEP2V(ub0, ub1, ub2,  ub0, ub1, ub2, role1);
  // role1 lanes 4-6: h = h1_fwd[j](T-1). ha(role0)/hb(role1) = h0_fwd(T-1).

  float e0 = role1 ? hb0 : ha0;
  float e1 = role1 ? hb1 : ha1;
  float e2 = role1 ? hb2 : ha2;

  // Layer-1 backward: one step from zero state (all lanes, own jc).
  float h1b;
  {
    float q_i = bih1r[r0] + bhh1r[r0]
              + Wih1r[r0*6+0]*e0 + Wih1r[r0*6+1]*e1 + Wih1r[r0*6+2]*e2
              + Wih1r[r0*6+3]*ub0 + Wih1r[r0*6+4]*ub1 + Wih1r[r0*6+5]*ub2;
    float q_g = bih1r[r2] + bhh1r[r2]
              + Wih1r[r2*6+0]*e0 + Wih1r[r2*6+1]*e1 + Wih1r[r2*6+2]*e2
              + Wih1r[r2*6+3]*ub0 + Wih1r[r2*6+4]*ub1 + Wih1r[r2*6+5]*ub2;
    float q_o = bih1r[r3] + bhh1r[r3]
              + Wih1r[r3*6+0]*e0 + Wih1r[r3*6+1]*e1 + Wih1r[r3*6+2]*e2
              + Wih1r[r3*6+3]*ub0 + Wih1r[r3*6+4]*ub1 + Wih1r[r3*6+5]*ub2;
    float ig = sigm_(q_i), gg = tanh_(q_g), og = sigm_(q_o);
    h1b = og * tanh_(ig * gg);          // c_prev = 0 -> f-gate drops out
  }

  float part = 0.f;
  if (role1) { if (j < 3) part = Wlin[j]     * h;   }
  else       { if (j < 3) part = Wlin[3 + j] * h1b; }
  part += __shfl_xor(part, 1, 8);
  part += __shfl_xor(part, 2, 8);
  part += __shfl_xor(part, 4, 8);
  if (lane == 0) out[b] = sigm_(part + blin[0]);
#undef LD2
#undef GATES2
#undef BCAST2
#undef STEP2
#undef STEP2V
#undef PROC2
}

extern "C" void kernel_launch(void* const* d_in, const int* in_sizes, int n_in,
                              void* d_out, int out_size, void* d_ws, size_t ws_size,
                              hipStream_t stream) {
  const float* x        = (const float*)d_in[0];
  const float* W_ih_l0  = (const float*)d_in[1];
  const float* W_hh_l0  = (const float*)d_in[2];
  const float* b_ih_l0  = (const float*)d_in[3];
  const float* b_hh_l0  = (const float*)d_in[4];
  const float* W_ih_l0r = (const float*)d_in[5];
  const float* W_hh_l0r = (const float*)d_in[6];
  const float* b_ih_l0r = (const float*)d_in[7];
  const float* b_hh_l0r = (const float*)d_in[8];
  const float* W_ih_l1  = (const float*)d_in[9];
  const float* W_hh_l1  = (const float*)d_in[10];
  const float* b_ih_l1  = (const float*)d_in[11];
  const float* b_hh_l1  = (const float*)d_in[12];
  const float* W_ih_l1r = (const float*)d_in[13];
  const float* W_hh_l1r = (const float*)d_in[14];
  const float* b_ih_l1r = (const float*)d_in[15];
  const float* b_hh_l1r = (const float*)d_in[16];
  const float* W_lin    = (const float*)d_in[17];
  const float* b_lin    = (const float*)d_in[18];

  float* y0b = (float*)d_ws;   // [B][64][3][8] fp32 = 48 MB, shifted layout
  float* out = (float*)d_out;

  lstm_l0_bwd<<<(B_ * 4) / 256, 256, 0, stream>>>(
      x, W_ih_l0r, W_hh_l0r, b_ih_l0r, b_hh_l0r, y0b);

  lstm_fused_fwd<<<(B_ * 8) / 256, 256, 0, stream>>>(
      x, W_ih_l0, W_hh_l0, b_ih_l0, b_hh_l0,
      W_ih_l1, W_hh_l1, b_ih_l1, b_hh_l1,
      W_ih_l1r, W_hh_l1r, b_ih_l1r, b_hh_l1r,
      W_lin, b_lin, y0b, out);
}